// Round 1
// baseline (257.858 us; speedup 1.0000x reference)
//
#include <hip/hip_runtime.h>

// SmoothTopKGate: per row of 8 floats, solve sum_i sigmoid((s_i - theta)/tau) = k
// (k=2, tau=0.01) by safeguarded Newton, then emit the sigmoids.
//
// Init at midpoint of 2nd/3rd largest (root provably within tau*ln(12)~0.025
// of it), clamp theta into [t3-0.03, t2+0.03] each step, floor the Newton
// denominator to avoid 0/0 in huge-gap rows (where theta precision doesn't
// affect the output anyway). 8 fixed iterations -> full per-row convergence;
// difference vs the reference's global-early-stop answer is bounded by the
// reference's own residual (~5e-4), well under the 2e-2 check threshold.

__global__ __launch_bounds__(256) void smooth_topk_kernel(
    const float* __restrict__ s, float* __restrict__ out, int nrows) {
  int row = blockIdx.x * blockDim.x + threadIdx.x;
  if (row >= nrows) return;

  const float4* sp = reinterpret_cast<const float4*>(s) + (size_t)row * 2;
  float4 a = sp[0];
  float4 b = sp[1];
  float v[8] = {a.x, a.y, a.z, a.w, b.x, b.y, b.z, b.w};

  const float C = 144.26950408889634f;  // 1/(tau*ln2), tau = 0.01

  // Branchless top-3 (t1 >= t2 >= t3) insertion, plus pre-scaled values.
  float vc[8];
  float t1 = -1e30f, t2 = -1e30f, t3 = -1e30f;
#pragma unroll
  for (int i = 0; i < 8; ++i) {
    float x = v[i];
    vc[i] = x * C;
    float hi1 = fmaxf(t1, x), lo1 = fminf(t1, x);
    t1 = hi1;
    float hi2 = fmaxf(t2, lo1), lo2 = fminf(t2, lo1);
    t2 = hi2;
    t3 = fmaxf(t3, lo2);
  }

  float theta = 0.5f * (t2 + t3);
  const float lo = t3 - 0.03f;  // root is provably inside (t3-0.025, t2+0.025)
  const float hi = t2 + 0.03f;

#pragma unroll
  for (int it = 0; it < 8; ++it) {
    float thC = theta * C;
    float f = -2.0f;  // sum(m) - k
    float g = 0.0f;   // sum(m*(1-m))  (= -tau * f')
#pragma unroll
    for (int i = 0; i < 8; ++i) {
      float e = exp2f(thC - vc[i]);                 // e -> inf below theta, 0 above
      float m = __builtin_amdgcn_rcpf(1.0f + e);    // rcp(inf)=0, rcp(1)=1: no NaN
      f += m;
      g = fmaf(m, 1.0f - m, g);                     // m=0 -> exactly 0 (inf-safe)
    }
    float step = f * 0.01f * __builtin_amdgcn_rcpf(fmaxf(g, 1e-12f));
    theta = fminf(fmaxf(theta + step, lo), hi);
  }

  float thC = theta * C;
  float o[8];
#pragma unroll
  for (int i = 0; i < 8; ++i) {
    float e = exp2f(thC - vc[i]);
    o[i] = __builtin_amdgcn_rcpf(1.0f + e);
  }
  float4* op = reinterpret_cast<float4*>(out) + (size_t)row * 2;
  op[0] = make_float4(o[0], o[1], o[2], o[3]);
  op[1] = make_float4(o[4], o[5], o[6], o[7]);
}

extern "C" void kernel_launch(void* const* d_in, const int* in_sizes, int n_in,
                              void* d_out, int out_size, void* d_ws, size_t ws_size,
                              hipStream_t stream) {
  const float* s = (const float*)d_in[0];
  float* out = (float*)d_out;
  int nrows = in_sizes[0] / 8;  // S_DIM = 8
  int block = 256;
  int grid = (nrows + block - 1) / block;
  smooth_topk_kernel<<<grid, block, 0, stream>>>(s, out, nrows);
}

// Round 2
// 218.097 us; speedup vs baseline: 1.1823x; 1.1823x over previous
//
#include <hip/hip_runtime.h>

// SmoothTopKGate: per row of 8 floats, solve sum_i sigmoid((s_i - theta)/tau) = k
// (k=2, tau=0.01) by safeguarded Newton, then emit the sigmoids.
//
// R2: raw v_exp_f32 via __builtin_amdgcn_exp2f (libm exp2f adds a ~6-op
// denormal fixup per call; 144 calls/row made R1 VALU-bound at 96%), and
// 8 -> 5 Newton iterations (init midpoint of t2/t3 is within ~2.5*tau of the
// root; Newton is quadratic; huge-gap rows saturate outputs so theta drift
// there is harmless).
//
// NOTE (correctness trap, do not "optimize"): g must be accumulated as
// fmaf(m, 1-m, g), NOT as f+2-sum(m^2). The latter cancels to exactly 0 for
// gap ~40*tau rows (top-side deficit invisible below float eps) while f~2e-9,
// and the floored denominator then slams theta to the clamp bound -> absmax
// ~0.95. With the fma form, |newton step| <= tau whenever tails are visible.

__global__ __launch_bounds__(256) void smooth_topk_kernel(
    const float* __restrict__ s, float* __restrict__ out, int nrows) {
  int row = blockIdx.x * blockDim.x + threadIdx.x;
  if (row >= nrows) return;

  const float4* sp = reinterpret_cast<const float4*>(s) + (size_t)row * 2;
  float4 a = sp[0];
  float4 b = sp[1];
  float v[8] = {a.x, a.y, a.z, a.w, b.x, b.y, b.z, b.w};

  const float C = 144.26950408889634f;  // 1/(tau*ln2), tau = 0.01

  // Branchless top-3 (t1 >= t2 >= t3) insertion, plus pre-scaled values.
  float vc[8];
  float t1 = -1e30f, t2 = -1e30f, t3 = -1e30f;
#pragma unroll
  for (int i = 0; i < 8; ++i) {
    float x = v[i];
    vc[i] = x * C;
    float hi1 = fmaxf(t1, x), lo1 = fminf(t1, x);
    t1 = hi1;
    float hi2 = fmaxf(t2, lo1), lo2 = fminf(t2, lo1);
    t2 = hi2;
    t3 = fmaxf(t3, lo2);
  }

  float theta = 0.5f * (t2 + t3);
  const float lo = t3 - 0.03f;  // root is provably inside (t3-0.025, t2+0.025)
  const float hi = t2 + 0.03f;

#pragma unroll
  for (int it = 0; it < 5; ++it) {
    float thC = theta * C;
    float f = -2.0f;  // sum(m) - k
    float g = 0.0f;   // sum(m*(1-m))  (= -tau * f')
#pragma unroll
    for (int i = 0; i < 8; ++i) {
      float e = __builtin_amdgcn_exp2f(thC - vc[i]);  // inf below theta, 0 above
      float m = __builtin_amdgcn_rcpf(1.0f + e);      // rcp(inf)=0, rcp(1)=1: no NaN
      f += m;
      g = fmaf(m, 1.0f - m, g);                       // m=0 -> exactly 0 (inf-safe)
    }
    float step = f * 0.01f * __builtin_amdgcn_rcpf(fmaxf(g, 1e-12f));
    theta = fminf(fmaxf(theta + step, lo), hi);
  }

  float thC = theta * C;
  float o[8];
#pragma unroll
  for (int i = 0; i < 8; ++i) {
    float e = __builtin_amdgcn_exp2f(thC - vc[i]);
    o[i] = __builtin_amdgcn_rcpf(1.0f + e);
  }
  float4* op = reinterpret_cast<float4*>(out) + (size_t)row * 2;
  op[0] = make_float4(o[0], o[1], o[2], o[3]);
  op[1] = make_float4(o[4], o[5], o[6], o[7]);
}

extern "C" void kernel_launch(void* const* d_in, const int* in_sizes, int n_in,
                              void* d_out, int out_size, void* d_ws, size_t ws_size,
                              hipStream_t stream) {
  const float* s = (const float*)d_in[0];
  float* out = (float*)d_out;
  int nrows = in_sizes[0] / 8;  // S_DIM = 8
  int block = 256;
  int grid = (nrows + block - 1) / block;
  smooth_topk_kernel<<<grid, block, 0, stream>>>(s, out, nrows);
}